// Round 1
// baseline (538.586 us; speedup 1.0000x reference)
//
#include <hip/hip_runtime.h>

#define N_ROWS   65536      // B*H*W
#define NE       1024
#define EDIM     256
#define HW       4096       // H*W
#define ZQ_ELEMS 16777216   // 16*256*64*64
#define LOSS_OFF 16777216
#define IDX_OFF  16777218

// ws layout (floats)
#define WS_CNORM 0          // 1024 floats
#define WS_PART  1024       // 4096 floats

#define BM 32
#define BN 128
#define BK 32
#define ZT_STRIDE 260       // 256 + 4 pad: row-step ≡ 4 mod 32 banks, 16B aligned
#define CS_KSTRIDE 33       // k-pad: group-step ≡ 4 mod 32 banks, 16B aligned

// ---------------- k0: codebook half-norms ----------------
__global__ __launch_bounds__(256) void k0_cnorm(const float* __restrict__ cb,
                                                float* __restrict__ ws) {
    int e = blockIdx.x * 256 + threadIdx.x;   // grid 4 x 256 = 1024
    const float4* row = (const float4*)(cb + (size_t)e * EDIM);
    float s = 0.f;
#pragma unroll
    for (int i = 0; i < EDIM / 4; ++i) {
        float4 v = row[i];
        s += v.x * v.x + v.y * v.y + v.z * v.z + v.w * v.w;
    }
    ws[WS_CNORM + e] = 0.5f * s;
}

// ---------------- k1: fused distance-GEMM + argmin ----------------
__global__ __launch_bounds__(256) void k1_argmin(const float* __restrict__ z,
                                                 const float* __restrict__ cb,
                                                 const float* __restrict__ cnorm,
                                                 float* __restrict__ out_idx) {
    __shared__ float zt[BM * ZT_STRIDE];            // [32][260]  33280 B
    __shared__ float cs[32 * CS_KSTRIDE * 4];       // [egrp32][k33][j4] 16896 B

    const int tid = threadIdx.x;
    const int tx = tid & 31;    // entry group 0..31  (entries tx*4..tx*4+3)
    const int ty = tid >> 5;    // row group 0..7     (rows ty*4..ty*4+3)
    const int n0 = blockIdx.x * BM;
    const int b   = n0 >> 12;
    const int hw0 = n0 & 4095;
    const float* zb = z + (size_t)b * (EDIM * HW);

    // stage z tile [32 rows][256 channels], float4 across rows (contiguous hw)
    {
        const int r4    = (tid & 7) * 4;
        const int kbase = tid >> 3;             // 0..31
#pragma unroll
        for (int kk = 0; kk < 8; ++kk) {
            int k = kbase + kk * 32;
            float4 v = *(const float4*)(zb + (size_t)k * HW + hw0 + r4);
            zt[(r4 + 0) * ZT_STRIDE + k] = v.x;
            zt[(r4 + 1) * ZT_STRIDE + k] = v.y;
            zt[(r4 + 2) * ZT_STRIDE + k] = v.z;
            zt[(r4 + 3) * ZT_STRIDE + k] = v.w;
        }
    }

    float best[4];
    int   bidx[4];
#pragma unroll
    for (int i = 0; i < 4; ++i) { best[i] = 1e30f; bidx[i] = 0; }

    for (int e0 = 0; e0 < NE; e0 += BN) {
        float acc[4][4];
#pragma unroll
        for (int i = 0; i < 4; ++i)
#pragma unroll
            for (int j = 0; j < 4; ++j) acc[i][j] = 0.f;

        for (int k0 = 0; k0 < EDIM; k0 += BK) {
            __syncthreads();   // protect cs (and first-iter zt) before restage
            // stage cs: 128 entries x 32 ks -> grouped [e>>2][k][e&3]
            {
                const int e  = tid >> 1;            // 0..127
                const int kb = (tid & 1) * 16;      // 0 or 16
                const float* crow = cb + (size_t)(e0 + e) * EDIM + k0 + kb;
                float* csp = &cs[(e >> 2) * (CS_KSTRIDE * 4) + (e & 3)];
#pragma unroll
                for (int q = 0; q < 4; ++q) {
                    float4 v = *(const float4*)(crow + q * 4);
                    int kk = kb + q * 4;
                    csp[(kk + 0) * 4] = v.x;
                    csp[(kk + 1) * 4] = v.y;
                    csp[(kk + 2) * 4] = v.z;
                    csp[(kk + 3) * 4] = v.w;
                }
            }
            __syncthreads();
            // compute: 4x4 micro-tile, vectorized LDS reads
            const float* ztp = &zt[(ty * 4) * ZT_STRIDE + k0];
            const float* csp = &cs[tx * (CS_KSTRIDE * 4)];
#pragma unroll 4
            for (int k = 0; k < BK; k += 4) {
                float zrf[4][4];   // [i][kk]
                float cef[4][4];   // [kk][j]
#pragma unroll
                for (int i = 0; i < 4; ++i) {
                    float4 v = *(const float4*)(ztp + i * ZT_STRIDE + k);
                    zrf[i][0] = v.x; zrf[i][1] = v.y; zrf[i][2] = v.z; zrf[i][3] = v.w;
                }
#pragma unroll
                for (int kk = 0; kk < 4; ++kk) {
                    float4 v = *(const float4*)(csp + (k + kk) * 4);
                    cef[kk][0] = v.x; cef[kk][1] = v.y; cef[kk][2] = v.z; cef[kk][3] = v.w;
                }
#pragma unroll
                for (int kk = 0; kk < 4; ++kk)
#pragma unroll
                    for (int i = 0; i < 4; ++i)
#pragma unroll
                        for (int j = 0; j < 4; ++j)
                            acc[i][j] = fmaf(zrf[i][kk], cef[kk][j], acc[i][j]);
            }
        }
        // argmin update: s = ||c||^2/2 - z.c  (d = ||z||^2 + 2s)
#pragma unroll
        for (int j = 0; j < 4; ++j) {
            int e = e0 + tx * 4 + j;
            float cn = cnorm[e];
#pragma unroll
            for (int i = 0; i < 4; ++i) {
                float s = cn - acc[i][j];
                if (s < best[i]) { best[i] = s; bidx[i] = e; }
            }
        }
    }

    // reduce across the 32 tx lanes (same 32-lane half of the wave)
#pragma unroll
    for (int m = 16; m >= 1; m >>= 1) {
#pragma unroll
        for (int i = 0; i < 4; ++i) {
            float ob = __shfl_xor(best[i], m, 64);
            int   oi = __shfl_xor(bidx[i], m, 64);
            if (ob < best[i] || (ob == best[i] && oi < bidx[i])) {
                best[i] = ob; bidx[i] = oi;
            }
        }
    }
    if (tx == 0) {
#pragma unroll
        for (int i = 0; i < 4; ++i)
            out_idx[n0 + ty * 4 + i] = (float)bidx[i];
    }
}

// ---------------- k2: gather z_q + fused loss partials ----------------
__global__ __launch_bounds__(256) void k2_scatter(const float* __restrict__ z,
                                                  const float* __restrict__ cb,
                                                  const float* __restrict__ idxf,
                                                  float* __restrict__ zq,
                                                  float* __restrict__ part) {
    __shared__ float ls[4];
    size_t base = (size_t)blockIdx.x * 256 + threadIdx.x;   // grid 4096
    float lsum = 0.f;
#pragma unroll
    for (int it = 0; it < 16; ++it) {
        size_t flat = base + (size_t)it * 1048576;
        int c  = (int)((flat >> 12) & 255);
        int n  = (int)(((flat >> 20) << 12) | (flat & 4095));
        int e  = (int)idxf[n];
        float q = cb[e * EDIM + c];
        zq[flat] = q;
        float d = q - z[flat];
        lsum += d * d;
    }
#pragma unroll
    for (int m = 32; m >= 1; m >>= 1) lsum += __shfl_down(lsum, m, 64);
    int lane = threadIdx.x & 63, w = threadIdx.x >> 6;
    if (lane == 0) ls[w] = lsum;
    __syncthreads();
    if (threadIdx.x == 0) part[blockIdx.x] = ls[0] + ls[1] + ls[2] + ls[3];
}

// ---------------- k3: final loss reduce + constants ----------------
__global__ __launch_bounds__(256) void k3_final(const float* __restrict__ part,
                                                float* __restrict__ dout) {
    __shared__ float ls[4];
    float s = 0.f;
#pragma unroll
    for (int it = 0; it < 16; ++it) s += part[threadIdx.x + it * 256];
#pragma unroll
    for (int m = 32; m >= 1; m >>= 1) s += __shfl_down(s, m, 64);
    int lane = threadIdx.x & 63, w = threadIdx.x >> 6;
    if (lane == 0) ls[w] = s;
    __syncthreads();
    if (threadIdx.x == 0) {
        float total = ls[0] + ls[1] + ls[2] + ls[3];
        dout[LOSS_OFF]     = total / 16777216.0f;
        dout[LOSS_OFF + 1] = 0.0f;
    }
}

extern "C" void kernel_launch(void* const* d_in, const int* in_sizes, int n_in,
                              void* d_out, int out_size, void* d_ws, size_t ws_size,
                              hipStream_t stream) {
    const float* z  = (const float*)d_in[0];
    const float* cb = (const float*)d_in[1];
    float* out = (float*)d_out;
    float* ws  = (float*)d_ws;

    hipLaunchKernelGGL(k0_cnorm,  dim3(4),    dim3(256), 0, stream, cb, ws + WS_CNORM);
    hipLaunchKernelGGL(k1_argmin, dim3(N_ROWS / BM), dim3(256), 0, stream,
                       z, cb, ws + WS_CNORM, out + IDX_OFF);
    hipLaunchKernelGGL(k2_scatter, dim3(4096), dim3(256), 0, stream,
                       z, cb, out + IDX_OFF, out, ws + WS_PART);
    hipLaunchKernelGGL(k3_final,  dim3(1),    dim3(256), 0, stream,
                       ws + WS_PART, out);
}